// Round 10
// baseline (162.022 us; speedup 1.0000x reference)
//
#include <hip/hip_runtime.h>

// DPQ network:
//  k_score : response argmax via split-bf16 MFMA; codebook A-fragments staged
//            in LDS (4-plane layout), 128 b's per wave (4 subtile-pairs);
//            certification margin + inline exact-f32 rescue; transposed output
//  k_finish: pure tile-transpose [c][b] -> [b][c]
//  k_gemm  : codebook-gather GEMM (bf16 MFMA), unchanged from passing rounds
// B=32768, C=32, K=256, D_SUB=16, D_IN=512, D_OUT=512

#define NB 32768
#define NC 32
#define NK 256
#define NDS 16
#define NDIN 512
#define NDOUT 512
#define CERT 0.02f

typedef __attribute__((ext_vector_type(8))) short s8v;   // 8 bf16 in 4 VGPRs
typedef __attribute__((ext_vector_type(4))) float f4v;   // MFMA accumulator

__device__ __forceinline__ unsigned short f2bf(float f) {
  unsigned int u = __float_as_uint(f);
  u += 0x7fffu + ((u >> 16) & 1u);   // RNE
  return (unsigned short)(u >> 16);
}
__device__ __forceinline__ float bf2f(unsigned short h) {
  return __uint_as_float(((unsigned int)h) << 16);
}

__device__ __forceinline__ void gload16(const void* g, void* l) {
  __builtin_amdgcn_global_load_lds(
      (const __attribute__((address_space(1))) void*)g,
      (__attribute__((address_space(3))) void*)l, 16, 0, 0);
}

// exact f32 dot over 16 dims, sequential fold (same association everywhere)
__device__ __forceinline__ float dot16(const float* x, const float* cj) {
  float4 a0 = *(const float4*)(x + 0),  a1 = *(const float4*)(x + 4);
  float4 a2 = *(const float4*)(x + 8),  a3 = *(const float4*)(x + 12);
  float4 c0 = *(const float4*)(cj + 0), c1 = *(const float4*)(cj + 4);
  float4 c2 = *(const float4*)(cj + 8), c3 = *(const float4*)(cj + 12);
  float s = a0.x * c0.x;
  s = fmaf(a0.y, c0.y, s); s = fmaf(a0.z, c0.z, s); s = fmaf(a0.w, c0.w, s);
  s = fmaf(a1.x, c1.x, s); s = fmaf(a1.y, c1.y, s); s = fmaf(a1.z, c1.z, s); s = fmaf(a1.w, c1.w, s);
  s = fmaf(a2.x, c2.x, s); s = fmaf(a2.y, c2.y, s); s = fmaf(a2.z, c2.z, s); s = fmaf(a2.w, c2.w, s);
  s = fmaf(a3.x, c3.x, s); s = fmaf(a3.y, c3.y, s); s = fmaf(a3.z, c3.z, s); s = fmaf(a3.w, c3.w, s);
  return s;
}

// ---------------------------------------------------------------------------
// Kernel 0: Wt[n][k] = bf16(W[k][n]); centsH = flat bf16 (gemm gather source);
//           centsP4[c][plane][k][8] = A-fragment-ordered hi/lo planes:
//           plane 0: hi d0-7, 1: hi d8-15, 2: lo d0-7, 3: lo d8-15
// ---------------------------------------------------------------------------
__global__ __launch_bounds__(256) void k_prep(const float* __restrict__ W,
                                              const float* __restrict__ cents,
                                              unsigned short* __restrict__ Wt,
                                              unsigned short* __restrict__ centsH,
                                              unsigned short* __restrict__ centsP4) {
  const int t = threadIdx.x;
  const int bid = blockIdx.x;
  if (bid < 256) {
    __shared__ float tile[32][33];
    const int k0 = (bid >> 4) << 5;
    const int n0 = (bid & 15) << 5;
    const int tx = t & 31, ty = t >> 5;
#pragma unroll
    for (int i = 0; i < 4; ++i) {
      int r = ty + i * 8;
      tile[r][tx] = W[(size_t)(k0 + r) * NDOUT + n0 + tx];
    }
    __syncthreads();
#pragma unroll
    for (int i = 0; i < 4; ++i) {
      int r = ty + i * 8;
      Wt[(size_t)(n0 + r) * NDIN + k0 + tx] = f2bf(tile[tx][r]);
    }
  } else {
    // per-c codebook processing: c = bid-256, thread t = k
    const int c = bid - 256;
    const int k = t;
    const float* src = cents + ((size_t)c * NK + k) * NDS;
    unsigned short hi[16], lo[16];
#pragma unroll
    for (int j = 0; j < 4; ++j) {
      float4 v = *(const float4*)(src + j * 4);
      unsigned short h0 = f2bf(v.x), h1 = f2bf(v.y), h2 = f2bf(v.z), h3 = f2bf(v.w);
      hi[j * 4 + 0] = h0; hi[j * 4 + 1] = h1; hi[j * 4 + 2] = h2; hi[j * 4 + 3] = h3;
      lo[j * 4 + 0] = f2bf(v.x - bf2f(h0));
      lo[j * 4 + 1] = f2bf(v.y - bf2f(h1));
      lo[j * 4 + 2] = f2bf(v.z - bf2f(h2));
      lo[j * 4 + 3] = f2bf(v.w - bf2f(h3));
    }
    // flat bf16 for gemm gather
    unsigned short* hf = centsH + ((size_t)c * NK + k) * NDS;
#pragma unroll
    for (int j = 0; j < 4; ++j)
      *(ushort4*)(hf + j * 4) = make_ushort4(hi[j * 4], hi[j * 4 + 1], hi[j * 4 + 2], hi[j * 4 + 3]);
    // 4-plane A-fragment layout
    unsigned short* pb = centsP4 + (size_t)c * 8192 + k * 8;
#pragma unroll
    for (int j = 0; j < 4; ++j) {
      *(ushort4*)(pb + 0 * 2048 + (j & 1) * 4) = make_ushort4(hi[(j & 1) * 4 + 0], hi[(j & 1) * 4 + 1],
                                                              hi[(j & 1) * 4 + 2], hi[(j & 1) * 4 + 3]);
    }
    *(ushort4*)(pb + 0 * 2048 + 0) = make_ushort4(hi[0], hi[1], hi[2], hi[3]);
    *(ushort4*)(pb + 0 * 2048 + 4) = make_ushort4(hi[4], hi[5], hi[6], hi[7]);
    *(ushort4*)(pb + 1 * 2048 + 0) = make_ushort4(hi[8], hi[9], hi[10], hi[11]);
    *(ushort4*)(pb + 1 * 2048 + 4) = make_ushort4(hi[12], hi[13], hi[14], hi[15]);
    *(ushort4*)(pb + 2 * 2048 + 0) = make_ushort4(lo[0], lo[1], lo[2], lo[3]);
    *(ushort4*)(pb + 2 * 2048 + 4) = make_ushort4(lo[4], lo[5], lo[6], lo[7]);
    *(ushort4*)(pb + 3 * 2048 + 0) = make_ushort4(lo[8], lo[9], lo[10], lo[11]);
    *(ushort4*)(pb + 3 * 2048 + 4) = make_ushort4(lo[12], lo[13], lo[14], lo[15]);
  }
}

// ---------------------------------------------------------------------------
// k_score: block = 4 waves, one c; codebook (16 KB, 4 planes) staged in LDS.
// Each wave: 128 b's as 4 subtile-pairs; per pair the MFMA core, tracking,
// butterfly, owner finalize and inline rescue are verbatim from passing R9.
// ---------------------------------------------------------------------------
__global__ __launch_bounds__(256, 4) void k_score(const float* __restrict__ inputs,
                                                  const unsigned short* __restrict__ centsP4,
                                                  const float* __restrict__ cents,
                                                  float* __restrict__ T_neg,
                                                  int* __restrict__ T_code) {
  __shared__ __align__(16) unsigned short AL[8192];   // 16 KB: plane*2048 + k*8 + j
  const int t = threadIdx.x;
  const int l = t & 63;
  const int w = t >> 6;
  const int c = blockIdx.y;

  // stage codebook planes (linear copy; layout already A-fragment-ordered)
  {
    const unsigned short* src = centsP4 + (size_t)c * 8192;
#pragma unroll
    for (int i = 0; i < 4; ++i)
      gload16(src + (i * 256 + t) * 8, (char*)AL + (i * 256 + t) * 16);
  }
  __syncthreads();

  const int g = l >> 4;
  const int col = l & 15;
  const int dh = (g & 1) * 8;
  const int g4 = g * 4;
  const unsigned short* abase = AL + g * 2048 + col * 8;  // a_kt = abase + kt*128
  const int wbase = blockIdx.x * 512 + w * 128;
  const f4v zz = {0.0f, 0.0f, 0.0f, 0.0f};

#pragma unroll 1
  for (int p = 0; p < 4; ++p) {
    const int b0 = wbase + p * 32;   // subtile0: b0+col, subtile1: b0+16+col

    // ---- B fragments (two subtiles), hi/lo split in-register (R9 verbatim)
    s8v bh0, bl0, bh1, bl1;
    {
      const float* r0 = inputs + ((size_t)(b0 + col) * NC + c) * NDS + dh;
      const float* r1 = inputs + ((size_t)(b0 + 16 + col) * NC + c) * NDS + dh;
      float4 u0 = *(const float4*)(r0), u1 = *(const float4*)(r0 + 4);
      float4 v0 = *(const float4*)(r1), v1 = *(const float4*)(r1 + 4);
      unsigned short h0 = f2bf(u0.x), h1 = f2bf(u0.y), h2 = f2bf(u0.z), h3 = f2bf(u0.w);
      unsigned short h4 = f2bf(u1.x), h5 = f2bf(u1.y), h6 = f2bf(u1.z), h7 = f2bf(u1.w);
      bh0 = s8v{(short)h0, (short)h1, (short)h2, (short)h3,
                (short)h4, (short)h5, (short)h6, (short)h7};
      bl0 = s8v{(short)f2bf(u0.x - bf2f(h0)), (short)f2bf(u0.y - bf2f(h1)),
                (short)f2bf(u0.z - bf2f(h2)), (short)f2bf(u0.w - bf2f(h3)),
                (short)f2bf(u1.x - bf2f(h4)), (short)f2bf(u1.y - bf2f(h5)),
                (short)f2bf(u1.z - bf2f(h6)), (short)f2bf(u1.w - bf2f(h7))};
      unsigned short j0 = f2bf(v0.x), j1 = f2bf(v0.y), j2 = f2bf(v0.z), j3 = f2bf(v0.w);
      unsigned short j4 = f2bf(v1.x), j5 = f2bf(v1.y), j6 = f2bf(v1.z), j7 = f2bf(v1.w);
      bh1 = s8v{(short)j0, (short)j1, (short)j2, (short)j3,
                (short)j4, (short)j5, (short)j6, (short)j7};
      bl1 = s8v{(short)f2bf(v0.x - bf2f(j0)), (short)f2bf(v0.y - bf2f(j1)),
                (short)f2bf(v0.z - bf2f(j2)), (short)f2bf(v0.w - bf2f(j3)),
                (short)f2bf(v1.x - bf2f(j4)), (short)f2bf(v1.y - bf2f(j5)),
                (short)f2bf(v1.z - bf2f(j6)), (short)f2bf(v1.w - bf2f(j7))};
      const s8v zer = {0, 0, 0, 0, 0, 0, 0, 0};
      if (l >= 32) { bl0 = zer; bl1 = zer; }
    }

    float best0 = -3.0e38f, sec0 = -3.0e38f;
    float best1 = -3.0e38f, sec1 = -3.0e38f;
    int bk0 = 0, bk1 = 0;

#pragma unroll
    for (int kt = 0; kt < 16; ++kt) {
      s8v a = *(const s8v*)(abase + kt * 128);   // LDS, 2-way-bank pattern
      f4v acc0 = __builtin_amdgcn_mfma_f32_16x16x32_bf16(a, bh0, zz, 0, 0, 0);
      acc0 = __builtin_amdgcn_mfma_f32_16x16x32_bf16(a, bl0, acc0, 0, 0, 0);
      f4v acc1 = __builtin_amdgcn_mfma_f32_16x16x32_bf16(a, bh1, zz, 0, 0, 0);
      acc1 = __builtin_amdgcn_mfma_f32_16x16x32_bf16(a, bl1, acc1, 0, 0, 0);
#pragma unroll
      for (int r = 0; r < 4; ++r) {
        const int kc = kt * 16 + r;
        float v = acc0[r];
        float mn = fminf(v, best0);
        sec0 = fmaxf(sec0, mn);
        bool gt = v > best0;
        bk0 = gt ? kc : bk0;
        best0 = fmaxf(best0, v);
        v = acc1[r];
        mn = fminf(v, best1);
        sec1 = fmaxf(sec1, mn);
        gt = v > best1;
        bk1 = gt ? kc : bk1;
        best1 = fmaxf(best1, v);
      }
    }
    bk0 += g4;
    bk1 += g4;

    // butterfly across the 4 lane-groups (R9 verbatim)
#pragma unroll
    for (int off = 16; off <= 32; off <<= 1) {
      float vb = __shfl_xor(best0, off);
      float sb = __shfl_xor(sec0, off);
      int kb = __shfl_xor(bk0, off);
      float mn = fminf(best0, vb);
      sec0 = fmaxf(fmaxf(sec0, sb), mn);
      bool take = (vb > best0) || (vb == best0 && kb < bk0);
      bk0 = take ? kb : bk0;
      best0 = fmaxf(best0, vb);

      vb = __shfl_xor(best1, off);
      sb = __shfl_xor(sec1, off);
      kb = __shfl_xor(bk1, off);
      mn = fminf(best1, vb);
      sec1 = fmaxf(fmaxf(sec1, sb), mn);
      take = (vb > best1) || (vb == best1 && kb < bk1);
      bk1 = take ? kb : bk1;
      best1 = fmaxf(best1, vb);
    }

    // per-result-lane final values (lanes 0..31 own b = b0 + l)
    const int sub = (l >> 4) & 1;
    float best = sub ? best1 : best0;
    float sec = sub ? sec1 : sec0;
    int bk = sub ? bk1 : bk0;
    const bool owner = (l < 32);
    const bool flagged = owner && (best - sec <= CERT);

    if (owner && !flagged) {
      const int b = b0 + l;
      const float* xr = inputs + ((size_t)b * NC + c) * NDS;
      const float* cr = cents + ((size_t)c * NK + bk) * NDS;
      size_t o = (size_t)c * NB + b;
      T_neg[o] = dot16(xr, cr);
      T_code[o] = bk;
    }

    // inline rescue: whole wave rescans flagged entries exactly (R9 verbatim)
    unsigned long long mask = __ballot(flagged);
    while (mask) {
      const int q = __builtin_ctzll(mask);
      mask &= mask - 1;
      const int b = b0 + q;
      const float* xr = inputs + ((size_t)b * NC + c) * NDS;
      const float* cr = cents + ((size_t)c * NK + l * 4) * NDS;
      float rb = -3.0e38f;
      int rk = 0;
#pragma unroll
      for (int qq = 0; qq < 4; ++qq) {
        float d = dot16(xr, cr + qq * NDS);
        if (d > rb) { rb = d; rk = l * 4 + qq; }
      }
#pragma unroll
      for (int off = 1; off <= 32; off <<= 1) {
        float vb = __shfl_xor(rb, off);
        int kb = __shfl_xor(rk, off);
        bool take = (vb > rb) || (vb == rb && kb < rk);
        rb = take ? vb : rb;
        rk = take ? kb : rk;
      }
      if (l == 0) {
        size_t o = (size_t)c * NB + b;
        T_neg[o] = rb;
        T_code[o] = rk;
      }
    }
  }
}

// ---------------------------------------------------------------------------
// k_finish: pure transpose (R9 verbatim)
// ---------------------------------------------------------------------------
__global__ __launch_bounds__(256) void k_finish(const float* __restrict__ T_neg,
                                                const int* __restrict__ T_code,
                                                float* __restrict__ negout,
                                                float* __restrict__ codefout,
                                                int* __restrict__ codeint) {
  __shared__ float sneg[64][33];
  __shared__ int scode[64][33];
  const int t = threadIdx.x;
  const int b0 = blockIdx.x * 64;

#pragma unroll
  for (int it = 0; it < 8; ++it) {
    int lin = it * 256 + t;
    int c = lin >> 6, bi = lin & 63;
    sneg[bi][c] = T_neg[(size_t)c * NB + b0 + bi];
    scode[bi][c] = T_code[(size_t)c * NB + b0 + bi];
  }
  __syncthreads();

#pragma unroll
  for (int it = 0; it < 8; ++it) {
    int lin = it * 256 + t;
    int bi = lin >> 5, c = lin & 31;
    size_t o = (size_t)(b0 + bi) * NC + c;
    int code = scode[bi][c];
    negout[o] = -sneg[bi][c];
    codefout[o] = (float)code;
    codeint[o] = code;
  }
}

// ---------------------------------------------------------------------------
// Kernel 2: product = gather(centsH, codes) @ W   via bf16 MFMA  (unchanged)
// ---------------------------------------------------------------------------
__global__ __launch_bounds__(256) void k_gemm(const unsigned short* __restrict__ centsB,
                                              const int* __restrict__ codeint,
                                              const unsigned short* __restrict__ Wt,
                                              float* __restrict__ out) {
  __shared__ __align__(16) unsigned short As[128 * 64];
  __shared__ __align__(16) unsigned short Bs[128 * 64];
  __shared__ int lcode[128 * 33];

  const int t = threadIdx.x;
  const int l = t & 63;
  const int w = t >> 6;
  const int wm = w >> 1, wn = w & 1;
  const int m0 = blockIdx.x * 128;
  const int n0 = blockIdx.y * 128;

  {
    const int4* cp = (const int4*)(codeint + (size_t)m0 * NC);
#pragma unroll
    for (int i = 0; i < 4; ++i) {
      int idx = t + i * 256;
      int4 v = cp[idx];
      int row = idx >> 3, col = (idx & 7) * 4;
      lcode[row * 33 + col + 0] = v.x;
      lcode[row * 33 + col + 1] = v.y;
      lcode[row * 33 + col + 2] = v.z;
      lcode[row * 33 + col + 3] = v.w;
    }
  }

  f4v acc[4][4] = {};
  const int s = t & 7;
  const int rq = t >> 3;

  for (int kt = 0; kt < 8; ++kt) {
    __syncthreads();
    const int c0 = kt * 4;
#pragma unroll
    for (int i = 0; i < 4; ++i) {
      int lr = i * 32 + rq;
      int srcslot = s ^ (lr & 7);
      int cl = srcslot >> 1, half = srcslot & 1;
      int code = lcode[lr * 33 + c0 + cl];
      const unsigned short* gsrc =
          centsB + ((size_t)((c0 + cl) * NK + code) * NDS + half * 8);
      gload16(gsrc, (char*)As + i * 4096 + (w << 10));
    }
#pragma unroll
    for (int i = 0; i < 4; ++i) {
      int lr = i * 32 + rq;
      int k16 = s ^ (lr & 7);
      const unsigned short* gsrc = Wt + (size_t)(n0 + lr) * NDIN + kt * 64 + k16 * 8;
      gload16(gsrc, (char*)Bs + i * 4096 + (w << 10));
    }
    __syncthreads();

    s8v af[4][2], bfr[4][2];
#pragma unroll
    for (int mf = 0; mf < 4; ++mf)
#pragma unroll
      for (int ks = 0; ks < 2; ++ks) {
        int row = wm * 64 + mf * 16 + (l & 15);
        int slot = ks * 4 + (l >> 4);
        af[mf][ks] = *(const s8v*)((const char*)As + row * 128 + ((slot ^ (row & 7)) << 4));
      }
#pragma unroll
    for (int nf = 0; nf < 4; ++nf)
#pragma unroll
      for (int ks = 0; ks < 2; ++ks) {
        int row = wn * 64 + nf * 16 + (l & 15);
        int slot = ks * 4 + (l >> 4);
        bfr[nf][ks] = *(const s8v*)((const char*)Bs + row * 128 + ((slot ^ (row & 7)) << 4));
      }
#pragma unroll
    for (int ks = 0; ks < 2; ++ks)
#pragma unroll
      for (int mf = 0; mf < 4; ++mf)
#pragma unroll
        for (int nf = 0; nf < 4; ++nf)
          acc[mf][nf] = __builtin_amdgcn_mfma_f32_16x16x32_bf16(
              af[mf][ks], bfr[nf][ks], acc[mf][nf], 0, 0, 0);
  }

#pragma unroll
  for (int mf = 0; mf < 4; ++mf)
#pragma unroll
    for (int nf = 0; nf < 4; ++nf)
#pragma unroll
      for (int r = 0; r < 4; ++r) {
        int row = m0 + wm * 64 + mf * 16 + (l >> 4) * 4 + r;
        int col = n0 + wn * 64 + nf * 16 + (l & 15);
        out[(size_t)row * NDOUT + col] = acc[mf][nf][r];
      }
}

// ---------------------------------------------------------------------------
extern "C" void kernel_launch(void* const* d_in, const int* in_sizes, int n_in,
                              void* d_out, int out_size, void* d_ws, size_t ws_size,
                              hipStream_t stream) {
  const float* inputs = (const float*)d_in[0];   // (B, C, 16) f32
  const float* cents  = (const float*)d_in[1];   // (C, K, 16) f32
  const float* W      = (const float*)d_in[2];   // (512, 512) f32

  float* out = (float*)d_out;
  float* negout   = out + (size_t)NB * NDOUT;            // (B, C)
  float* codefout = negout + (size_t)NB * NC;            // (B, C) as float

  unsigned short* Wt      = (unsigned short*)d_ws;                          // 512 KiB
  unsigned short* centsH  = (unsigned short*)((char*)d_ws + 512 * 1024);    // 256 KiB
  unsigned short* centsP4 = (unsigned short*)((char*)d_ws + (1 << 20));     // 512 KiB
  int* codeint            = (int*)((char*)d_ws + 2 * (1 << 20));            // 4 MiB
  float* T_neg            = (float*)((char*)d_ws + 6 * (1 << 20));          // 4 MiB
  int* T_code             = (int*)((char*)d_ws + 10 * (1 << 20));           // 4 MiB

  k_prep<<<288, 256, 0, stream>>>(W, cents, Wt, centsH, centsP4);
  k_score<<<dim3(NB / 512, NC), 256, 0, stream>>>(inputs, centsP4, cents, T_neg, T_code);
  k_finish<<<NB / 64, 256, 0, stream>>>(T_neg, T_code, negout, codefout, codeint);
  k_gemm<<<dim3(NB / 128, NDOUT / 128), 256, 0, stream>>>(centsH, codeint, Wt, out);
}

// Round 11
// 124.462 us; speedup vs baseline: 1.3018x; 1.3018x over previous
//
#include <hip/hip_runtime.h>

// DPQ network:
//  k_score : response argmax via split-bf16 MFMA; 16 A-fragments hoisted into
//            registers (one load burst, zero memory ops in the kt loop);
//            certification margin + inline exact-f32 rescue; transposed output
//  k_finish: pure tile-transpose [c][b] -> [b][c]
//  k_gemm  : codebook-gather GEMM (bf16 MFMA), unchanged from passing rounds
// B=32768, C=32, K=256, D_SUB=16, D_IN=512, D_OUT=512

#define NB 32768
#define NC 32
#define NK 256
#define NDS 16
#define NDIN 512
#define NDOUT 512
#define CERT 0.02f

typedef __attribute__((ext_vector_type(8))) short s8v;   // 8 bf16 in 4 VGPRs
typedef __attribute__((ext_vector_type(4))) float f4v;   // MFMA accumulator

__device__ __forceinline__ unsigned short f2bf(float f) {
  unsigned int u = __float_as_uint(f);
  u += 0x7fffu + ((u >> 16) & 1u);   // RNE
  return (unsigned short)(u >> 16);
}
__device__ __forceinline__ float bf2f(unsigned short h) {
  return __uint_as_float(((unsigned int)h) << 16);
}

__device__ __forceinline__ void gload16(const void* g, void* l) {
  __builtin_amdgcn_global_load_lds(
      (const __attribute__((address_space(1))) void*)g,
      (__attribute__((address_space(3))) void*)l, 16, 0, 0);
}

// exact f32 dot over 16 dims, sequential fold (same association everywhere)
__device__ __forceinline__ float dot16(const float* x, const float* cj) {
  float4 a0 = *(const float4*)(x + 0),  a1 = *(const float4*)(x + 4);
  float4 a2 = *(const float4*)(x + 8),  a3 = *(const float4*)(x + 12);
  float4 c0 = *(const float4*)(cj + 0), c1 = *(const float4*)(cj + 4);
  float4 c2 = *(const float4*)(cj + 8), c3 = *(const float4*)(cj + 12);
  float s = a0.x * c0.x;
  s = fmaf(a0.y, c0.y, s); s = fmaf(a0.z, c0.z, s); s = fmaf(a0.w, c0.w, s);
  s = fmaf(a1.x, c1.x, s); s = fmaf(a1.y, c1.y, s); s = fmaf(a1.z, c1.z, s); s = fmaf(a1.w, c1.w, s);
  s = fmaf(a2.x, c2.x, s); s = fmaf(a2.y, c2.y, s); s = fmaf(a2.z, c2.z, s); s = fmaf(a2.w, c2.w, s);
  s = fmaf(a3.x, c3.x, s); s = fmaf(a3.y, c3.y, s); s = fmaf(a3.z, c3.z, s); s = fmaf(a3.w, c3.w, s);
  return s;
}

// ---------------------------------------------------------------------------
// Kernel 0: Wt[n][k] = bf16(W[k][n]); centsH = flat bf16 (gemm gather source);
//           centsP4[c][plane][k][8] = A-fragment-ordered hi/lo planes:
//           plane 0: hi d0-7, 1: hi d8-15, 2: lo d0-7, 3: lo d8-15
// ---------------------------------------------------------------------------
__global__ __launch_bounds__(256) void k_prep(const float* __restrict__ W,
                                              const float* __restrict__ cents,
                                              unsigned short* __restrict__ Wt,
                                              unsigned short* __restrict__ centsH,
                                              unsigned short* __restrict__ centsP4) {
  const int t = threadIdx.x;
  const int bid = blockIdx.x;
  if (bid < 256) {
    __shared__ float tile[32][33];
    const int k0 = (bid >> 4) << 5;
    const int n0 = (bid & 15) << 5;
    const int tx = t & 31, ty = t >> 5;
#pragma unroll
    for (int i = 0; i < 4; ++i) {
      int r = ty + i * 8;
      tile[r][tx] = W[(size_t)(k0 + r) * NDOUT + n0 + tx];
    }
    __syncthreads();
#pragma unroll
    for (int i = 0; i < 4; ++i) {
      int r = ty + i * 8;
      Wt[(size_t)(n0 + r) * NDIN + k0 + tx] = f2bf(tile[tx][r]);
    }
  } else {
    // per-c codebook processing: c = bid-256, thread t = k
    const int c = bid - 256;
    const int k = t;
    const float* src = cents + ((size_t)c * NK + k) * NDS;
    unsigned short hi[16], lo[16];
#pragma unroll
    for (int j = 0; j < 4; ++j) {
      float4 v = *(const float4*)(src + j * 4);
      unsigned short h0 = f2bf(v.x), h1 = f2bf(v.y), h2 = f2bf(v.z), h3 = f2bf(v.w);
      hi[j * 4 + 0] = h0; hi[j * 4 + 1] = h1; hi[j * 4 + 2] = h2; hi[j * 4 + 3] = h3;
      lo[j * 4 + 0] = f2bf(v.x - bf2f(h0));
      lo[j * 4 + 1] = f2bf(v.y - bf2f(h1));
      lo[j * 4 + 2] = f2bf(v.z - bf2f(h2));
      lo[j * 4 + 3] = f2bf(v.w - bf2f(h3));
    }
    // flat bf16 for gemm gather
    unsigned short* hf = centsH + ((size_t)c * NK + k) * NDS;
#pragma unroll
    for (int j = 0; j < 4; ++j)
      *(ushort4*)(hf + j * 4) = make_ushort4(hi[j * 4], hi[j * 4 + 1], hi[j * 4 + 2], hi[j * 4 + 3]);
    // 4-plane A-fragment layout
    unsigned short* pb = centsP4 + (size_t)c * 8192 + k * 8;
    *(ushort4*)(pb + 0 * 2048 + 0) = make_ushort4(hi[0], hi[1], hi[2], hi[3]);
    *(ushort4*)(pb + 0 * 2048 + 4) = make_ushort4(hi[4], hi[5], hi[6], hi[7]);
    *(ushort4*)(pb + 1 * 2048 + 0) = make_ushort4(hi[8], hi[9], hi[10], hi[11]);
    *(ushort4*)(pb + 1 * 2048 + 4) = make_ushort4(hi[12], hi[13], hi[14], hi[15]);
    *(ushort4*)(pb + 2 * 2048 + 0) = make_ushort4(lo[0], lo[1], lo[2], lo[3]);
    *(ushort4*)(pb + 2 * 2048 + 4) = make_ushort4(lo[4], lo[5], lo[6], lo[7]);
    *(ushort4*)(pb + 3 * 2048 + 0) = make_ushort4(lo[8], lo[9], lo[10], lo[11]);
    *(ushort4*)(pb + 3 * 2048 + 4) = make_ushort4(lo[12], lo[13], lo[14], lo[15]);
  }
}

// ---------------------------------------------------------------------------
// k_score: per wave = 32 b's x 1 c (R9 grid). 16 A-fragments hoisted into
// registers (one independent load burst, centsP4 plane layout); kt loop is
// pure register MFMA + tracking. Finalize/rescue verbatim from passing R9.
// ---------------------------------------------------------------------------
__global__ __launch_bounds__(256, 4) void k_score(const float* __restrict__ inputs,
                                                  const unsigned short* __restrict__ centsP4,
                                                  const float* __restrict__ cents,
                                                  float* __restrict__ T_neg,
                                                  int* __restrict__ T_code) {
  const int t = threadIdx.x;
  const int l = t & 63;
  const int w = t >> 6;
  const int c = blockIdx.y;
  const int b0 = blockIdx.x * 128 + w * 32;   // this wave: b0..b0+31 (two 16-col subtiles)
  const int g = l >> 4;
  const int col = l & 15;
  const int dh = (g & 1) * 8;
  const int g4 = g * 4;

  // ---- hoist all 16 A-fragments into registers (independent 16B loads)
  // lane (g,col), tile kt: plane g, row kt*16+col, 8 elems
  const unsigned short* abase = centsP4 + (size_t)c * 8192 + g * 2048 + col * 8;
  s8v areg[16];
#pragma unroll
  for (int kt = 0; kt < 16; ++kt)
    areg[kt] = *(const s8v*)(abase + kt * 128);

  // ---- B fragments (two subtiles), hi/lo split in-register (R9 verbatim)
  s8v bh0, bl0, bh1, bl1;
  {
    const float* r0 = inputs + ((size_t)(b0 + col) * NC + c) * NDS + dh;
    const float* r1 = inputs + ((size_t)(b0 + 16 + col) * NC + c) * NDS + dh;
    float4 u0 = *(const float4*)(r0), u1 = *(const float4*)(r0 + 4);
    float4 v0 = *(const float4*)(r1), v1 = *(const float4*)(r1 + 4);
    unsigned short h0 = f2bf(u0.x), h1 = f2bf(u0.y), h2 = f2bf(u0.z), h3 = f2bf(u0.w);
    unsigned short h4 = f2bf(u1.x), h5 = f2bf(u1.y), h6 = f2bf(u1.z), h7 = f2bf(u1.w);
    bh0 = s8v{(short)h0, (short)h1, (short)h2, (short)h3,
              (short)h4, (short)h5, (short)h6, (short)h7};
    bl0 = s8v{(short)f2bf(u0.x - bf2f(h0)), (short)f2bf(u0.y - bf2f(h1)),
              (short)f2bf(u0.z - bf2f(h2)), (short)f2bf(u0.w - bf2f(h3)),
              (short)f2bf(u1.x - bf2f(h4)), (short)f2bf(u1.y - bf2f(h5)),
              (short)f2bf(u1.z - bf2f(h6)), (short)f2bf(u1.w - bf2f(h7))};
    unsigned short j0 = f2bf(v0.x), j1 = f2bf(v0.y), j2 = f2bf(v0.z), j3 = f2bf(v0.w);
    unsigned short j4 = f2bf(v1.x), j5 = f2bf(v1.y), j6 = f2bf(v1.z), j7 = f2bf(v1.w);
    bh1 = s8v{(short)j0, (short)j1, (short)j2, (short)j3,
              (short)j4, (short)j5, (short)j6, (short)j7};
    bl1 = s8v{(short)f2bf(v0.x - bf2f(j0)), (short)f2bf(v0.y - bf2f(j1)),
              (short)f2bf(v0.z - bf2f(j2)), (short)f2bf(v0.w - bf2f(j3)),
              (short)f2bf(v1.x - bf2f(j4)), (short)f2bf(v1.y - bf2f(j5)),
              (short)f2bf(v1.z - bf2f(j6)), (short)f2bf(v1.w - bf2f(j7))};
    const s8v zer = {0, 0, 0, 0, 0, 0, 0, 0};
    if (l >= 32) { bl0 = zer; bl1 = zer; }    // kappa>=16 of pass-2 B is zero
  }

  float best0 = -3.0e38f, sec0 = -3.0e38f;
  float best1 = -3.0e38f, sec1 = -3.0e38f;
  int bk0 = 0, bk1 = 0;
  const f4v zz = {0.0f, 0.0f, 0.0f, 0.0f};

#pragma unroll
  for (int kt = 0; kt < 16; ++kt) {
    s8v a = areg[kt];                          // register-resident
    f4v acc0 = __builtin_amdgcn_mfma_f32_16x16x32_bf16(a, bh0, zz, 0, 0, 0);
    acc0 = __builtin_amdgcn_mfma_f32_16x16x32_bf16(a, bl0, acc0, 0, 0, 0);
    f4v acc1 = __builtin_amdgcn_mfma_f32_16x16x32_bf16(a, bh1, zz, 0, 0, 0);
    acc1 = __builtin_amdgcn_mfma_f32_16x16x32_bf16(a, bl1, acc1, 0, 0, 0);
#pragma unroll
    for (int r = 0; r < 4; ++r) {
      const int kc = kt * 16 + r;             // + g4 folded at the end
      float v = acc0[r];
      float mn = fminf(v, best0);
      sec0 = fmaxf(sec0, mn);
      bool gt = v > best0;
      bk0 = gt ? kc : bk0;
      best0 = fmaxf(best0, v);
      v = acc1[r];
      mn = fminf(v, best1);
      sec1 = fmaxf(sec1, mn);
      gt = v > best1;
      bk1 = gt ? kc : bk1;
      best1 = fmaxf(best1, v);
    }
  }
  bk0 += g4;
  bk1 += g4;

  // butterfly across the 4 lane-groups (R9 verbatim)
#pragma unroll
  for (int off = 16; off <= 32; off <<= 1) {
    float vb = __shfl_xor(best0, off);
    float sb = __shfl_xor(sec0, off);
    int kb = __shfl_xor(bk0, off);
    float mn = fminf(best0, vb);
    sec0 = fmaxf(fmaxf(sec0, sb), mn);
    bool take = (vb > best0) || (vb == best0 && kb < bk0);
    bk0 = take ? kb : bk0;
    best0 = fmaxf(best0, vb);

    vb = __shfl_xor(best1, off);
    sb = __shfl_xor(sec1, off);
    kb = __shfl_xor(bk1, off);
    mn = fminf(best1, vb);
    sec1 = fmaxf(fmaxf(sec1, sb), mn);
    take = (vb > best1) || (vb == best1 && kb < bk1);
    bk1 = take ? kb : bk1;
    best1 = fmaxf(best1, vb);
  }

  // per-result-lane final values (lanes 0..31 own b = b0 + l)
  const int sub = (l >> 4) & 1;
  float best = sub ? best1 : best0;
  float sec = sub ? sec1 : sec0;
  int bk = sub ? bk1 : bk0;
  const bool owner = (l < 32);
  const bool flagged = owner && (best - sec <= CERT);

  // certified entries: exact f32 value for the winner, store
  if (owner && !flagged) {
    const int b = b0 + l;
    const float* xr = inputs + ((size_t)b * NC + c) * NDS;
    const float* cr = cents + ((size_t)c * NK + bk) * NDS;
    size_t o = (size_t)c * NB + b;
    T_neg[o] = dot16(xr, cr);
    T_code[o] = bk;
  }

  // inline rescue: whole wave rescans flagged entries exactly (R9 verbatim)
  unsigned long long mask = __ballot(flagged);
  while (mask) {
    const int p = __builtin_ctzll(mask);
    mask &= mask - 1;
    const int b = b0 + p;
    const float* xr = inputs + ((size_t)b * NC + c) * NDS;
    const float* cr = cents + ((size_t)c * NK + l * 4) * NDS;
    float rb = -3.0e38f;
    int rk = 0;
#pragma unroll
    for (int q = 0; q < 4; ++q) {
      float d = dot16(xr, cr + q * NDS);
      if (d > rb) { rb = d; rk = l * 4 + q; }   // strict >, ascending k
    }
#pragma unroll
    for (int off = 1; off <= 32; off <<= 1) {
      float vb = __shfl_xor(rb, off);
      int kb = __shfl_xor(rk, off);
      bool take = (vb > rb) || (vb == rb && kb < rk);
      rb = take ? vb : rb;
      rk = take ? kb : rk;
    }
    if (l == 0) {
      size_t o = (size_t)c * NB + b;
      T_neg[o] = rb;
      T_code[o] = rk;
    }
  }
}

// ---------------------------------------------------------------------------
// k_finish: pure transpose (R9 verbatim)
// ---------------------------------------------------------------------------
__global__ __launch_bounds__(256) void k_finish(const float* __restrict__ T_neg,
                                                const int* __restrict__ T_code,
                                                float* __restrict__ negout,
                                                float* __restrict__ codefout,
                                                int* __restrict__ codeint) {
  __shared__ float sneg[64][33];
  __shared__ int scode[64][33];
  const int t = threadIdx.x;
  const int b0 = blockIdx.x * 64;

#pragma unroll
  for (int it = 0; it < 8; ++it) {
    int lin = it * 256 + t;
    int c = lin >> 6, bi = lin & 63;
    sneg[bi][c] = T_neg[(size_t)c * NB + b0 + bi];
    scode[bi][c] = T_code[(size_t)c * NB + b0 + bi];
  }
  __syncthreads();

#pragma unroll
  for (int it = 0; it < 8; ++it) {
    int lin = it * 256 + t;
    int bi = lin >> 5, c = lin & 31;
    size_t o = (size_t)(b0 + bi) * NC + c;
    int code = scode[bi][c];
    negout[o] = -sneg[bi][c];
    codefout[o] = (float)code;
    codeint[o] = code;
  }
}

// ---------------------------------------------------------------------------
// Kernel 2: product = gather(centsH, codes) @ W   via bf16 MFMA  (unchanged)
// ---------------------------------------------------------------------------
__global__ __launch_bounds__(256) void k_gemm(const unsigned short* __restrict__ centsB,
                                              const int* __restrict__ codeint,
                                              const unsigned short* __restrict__ Wt,
                                              float* __restrict__ out) {
  __shared__ __align__(16) unsigned short As[128 * 64];
  __shared__ __align__(16) unsigned short Bs[128 * 64];
  __shared__ int lcode[128 * 33];

  const int t = threadIdx.x;
  const int l = t & 63;
  const int w = t >> 6;
  const int wm = w >> 1, wn = w & 1;
  const int m0 = blockIdx.x * 128;
  const int n0 = blockIdx.y * 128;

  {
    const int4* cp = (const int4*)(codeint + (size_t)m0 * NC);
#pragma unroll
    for (int i = 0; i < 4; ++i) {
      int idx = t + i * 256;
      int4 v = cp[idx];
      int row = idx >> 3, col = (idx & 7) * 4;
      lcode[row * 33 + col + 0] = v.x;
      lcode[row * 33 + col + 1] = v.y;
      lcode[row * 33 + col + 2] = v.z;
      lcode[row * 33 + col + 3] = v.w;
    }
  }

  f4v acc[4][4] = {};
  const int s = t & 7;
  const int rq = t >> 3;

  for (int kt = 0; kt < 8; ++kt) {
    __syncthreads();
    const int c0 = kt * 4;
#pragma unroll
    for (int i = 0; i < 4; ++i) {
      int lr = i * 32 + rq;
      int srcslot = s ^ (lr & 7);
      int cl = srcslot >> 1, half = srcslot & 1;
      int code = lcode[lr * 33 + c0 + cl];
      const unsigned short* gsrc =
          centsB + ((size_t)((c0 + cl) * NK + code) * NDS + half * 8);
      gload16(gsrc, (char*)As + i * 4096 + (w << 10));
    }
#pragma unroll
    for (int i = 0; i < 4; ++i) {
      int lr = i * 32 + rq;
      int k16 = s ^ (lr & 7);
      const unsigned short* gsrc = Wt + (size_t)(n0 + lr) * NDIN + kt * 64 + k16 * 8;
      gload16(gsrc, (char*)Bs + i * 4096 + (w << 10));
    }
    __syncthreads();

    s8v af[4][2], bfr[4][2];
#pragma unroll
    for (int mf = 0; mf < 4; ++mf)
#pragma unroll
      for (int ks = 0; ks < 2; ++ks) {
        int row = wm * 64 + mf * 16 + (l & 15);
        int slot = ks * 4 + (l >> 4);
        af[mf][ks] = *(const s8v*)((const char*)As + row * 128 + ((slot ^ (row & 7)) << 4));
      }
#pragma unroll
    for (int nf = 0; nf < 4; ++nf)
#pragma unroll
      for (int ks = 0; ks < 2; ++ks) {
        int row = wn * 64 + nf * 16 + (l & 15);
        int slot = ks * 4 + (l >> 4);
        bfr[nf][ks] = *(const s8v*)((const char*)Bs + row * 128 + ((slot ^ (row & 7)) << 4));
      }
#pragma unroll
    for (int ks = 0; ks < 2; ++ks)
#pragma unroll
      for (int mf = 0; mf < 4; ++mf)
#pragma unroll
        for (int nf = 0; nf < 4; ++nf)
          acc[mf][nf] = __builtin_amdgcn_mfma_f32_16x16x32_bf16(
              af[mf][ks], bfr[nf][ks], acc[mf][nf], 0, 0, 0);
  }

#pragma unroll
  for (int mf = 0; mf < 4; ++mf)
#pragma unroll
    for (int nf = 0; nf < 4; ++nf)
#pragma unroll
      for (int r = 0; r < 4; ++r) {
        int row = m0 + wm * 64 + mf * 16 + (l >> 4) * 4 + r;
        int col = n0 + wn * 64 + nf * 16 + (l & 15);
        out[(size_t)row * NDOUT + col] = acc[mf][nf][r];
      }
}

// ---------------------------------------------------------------------------
extern "C" void kernel_launch(void* const* d_in, const int* in_sizes, int n_in,
                              void* d_out, int out_size, void* d_ws, size_t ws_size,
                              hipStream_t stream) {
  const float* inputs = (const float*)d_in[0];   // (B, C, 16) f32
  const float* cents  = (const float*)d_in[1];   // (C, K, 16) f32
  const float* W      = (const float*)d_in[2];   // (512, 512) f32

  float* out = (float*)d_out;
  float* negout   = out + (size_t)NB * NDOUT;            // (B, C)
  float* codefout = negout + (size_t)NB * NC;            // (B, C) as float

  unsigned short* Wt      = (unsigned short*)d_ws;                          // 512 KiB
  unsigned short* centsH  = (unsigned short*)((char*)d_ws + 512 * 1024);    // 256 KiB
  unsigned short* centsP4 = (unsigned short*)((char*)d_ws + (1 << 20));     // 512 KiB
  int* codeint            = (int*)((char*)d_ws + 2 * (1 << 20));            // 4 MiB
  float* T_neg            = (float*)((char*)d_ws + 6 * (1 << 20));          // 4 MiB
  int* T_code             = (int*)((char*)d_ws + 10 * (1 << 20));           // 4 MiB

  k_prep<<<288, 256, 0, stream>>>(W, cents, Wt, centsH, centsP4);
  k_score<<<dim3(NB / 128, NC), 256, 0, stream>>>(inputs, centsP4, cents, T_neg, T_code);
  k_finish<<<NB / 64, 256, 0, stream>>>(T_neg, T_code, negout, codefout, codeint);
  k_gemm<<<dim3(NB / 128, NDOUT / 128), 256, 0, stream>>>(centsH, codeint, Wt, out);
}